// Round 11
// baseline (226.346 us; speedup 1.0000x reference)
//
#include <hip/hip_runtime.h>
#include <hip/hip_bf16.h>

typedef __attribute__((ext_vector_type(4))) float f32x4;
typedef __attribute__((ext_vector_type(8))) short bf16x8;

#define NROWS 32768
#define DIM   2048
#define NEXP  64
#define BKF   128              // K-chunk (f32 elements)
#define NCH   (DIM / BKF)      // 16 chunks

__device__ __forceinline__ short f2bf(float f) {
    __hip_bfloat16 h = __float2bfloat16(f);   // RTNE
    short s;
    __builtin_memcpy(&s, &h, 2);
    return s;
}

// async global->LDS DMA, 16B per lane; LDS dest wave-uniform (HW adds lane*16).
__device__ __forceinline__ void async16(const void* g, void* l) {
    __builtin_amdgcn_global_load_lds(
        (const __attribute__((address_space(1))) unsigned int*)g,
        (__attribute__((address_space(3))) unsigned int*)l, 16, 0, 0);
}

// ---------------- Kernel A: expert prep -------------------------------------
__global__ __launch_bounds__(256) void prep_experts(
    const float* __restrict__ ek,
    short* __restrict__ ekbf,
    short* __restrict__ ekT,
    float* __restrict__ enorm)
{
    const int e = blockIdx.x;
    const int t = threadIdx.x;
    const float* row = ek + e * DIM;
    float ss = 0.f;
#pragma unroll
    for (int i = 0; i < 2; ++i) {
        const int c4 = t + i * 256;
        const float4 v = ((const float4*)row)[c4];
        ss += v.x * v.x + v.y * v.y + v.z * v.z + v.w * v.w;
        short4 b;
        b.x = f2bf(v.x); b.y = f2bf(v.y); b.z = f2bf(v.z); b.w = f2bf(v.w);
        *(short4*)(ekbf + e * DIM + c4 * 4) = b;
        const int d = c4 * 4;
        ekT[(d + 0) * NEXP + e] = b.x;
        ekT[(d + 1) * NEXP + e] = b.y;
        ekT[(d + 2) * NEXP + e] = b.z;
        ekT[(d + 3) * NEXP + e] = b.w;
    }
#pragma unroll
    for (int s = 1; s < 64; s <<= 1) ss += __shfl_xor(ss, s);
    __shared__ float red[4];
    if ((t & 63) == 0) red[t >> 6] = ss;
    __syncthreads();
    if (t == 0) enorm[e] = sqrtf(red[0] + red[1] + red[2] + red[3]);
}

// ---------------- Kernel 1: similarity (read-bound) — R6 structure ----------
__global__ __launch_bounds__(256) void sim_kernel(
    const float* __restrict__ z,
    const short* __restrict__ ekbf,   // [64][2048] bf16
    const float* __restrict__ enorm,  // [64]
    float* __restrict__ out_sim)      // [32768][64]
{
    const int tid = threadIdx.x;
    const int w   = tid >> 6;
    const int l   = tid & 63;
    const int lr  = l & 15;
    const int lg  = l >> 4;
    const int base = blockIdx.x * 32;

    __shared__ __align__(16) float zbuf[2][32][BKF];   // 2 x 16 KiB
    __shared__ __align__(16) short ebuf[2][64][BKF];   // 2 x 16 KiB

    f32x4 acc[2];
    acc[0] = f32x4{0.f, 0.f, 0.f, 0.f};
    acc[1] = f32x4{0.f, 0.f, 0.f, 0.f};
    float sqa[2] = {0.f, 0.f}, sqb[2] = {0.f, 0.f};

    auto STAGE = [&](int c_) {
        const int b_ = c_ & 1;
#pragma unroll
        for (int i = 0; i < 4; ++i) {               // z rows w*8 .. w*8+7
            const int r0 = w * 8 + i * 2;
            const int zr = r0 + (l >> 5);           // 2 rows/instr (512B each)
            async16(z + (size_t)(base + zr) * DIM + c_ * BKF
                      + (((l & 31) ^ (zr & 7)) << 2),
                    &zbuf[b_][r0][0]);
        }
#pragma unroll
        for (int i = 0; i < 4; ++i) {               // ek rows w*16 .. w*16+15
            const int r0 = w * 16 + i * 4;
            const int er = r0 + (l >> 4);           // 4 rows/instr (256B each)
            async16(ekbf + (size_t)er * DIM + c_ * BKF
                         + (((l & 15) ^ (er & 7)) << 3),
                    &ebuf[b_][r0][0]);
        }
    };

    STAGE(0); STAGE(1);                              // 16 DMAs/wave in flight

    for (int c = 0; c < NCH; ++c) {
        if (c < NCH - 1) asm volatile("s_waitcnt vmcnt(8)" ::: "memory");
        else             asm volatile("s_waitcnt vmcnt(0)" ::: "memory");
        __builtin_amdgcn_s_barrier();
        __builtin_amdgcn_sched_barrier(0);
        const int b = c & 1;

#pragma unroll
        for (int kk = 0; kk < BKF / 32; ++kk) {
            const int eu = ((kk * 4 + lg) ^ (lr & 7)) << 4;
            const bf16x8 bf =
                *(const bf16x8*)((const char*)&ebuf[b][w * 16 + lr][0] + eu);
#pragma unroll
            for (int mt = 0; mt < 2; ++mt) {
                const int zr = mt * 16 + lr;
                const int u0 = ((kk * 8 + lg * 2)     ^ (lr & 7)) << 4;
                const int u1 = ((kk * 8 + lg * 2 + 1) ^ (lr & 7)) << 4;
                const float4 a0 = *(const float4*)((const char*)&zbuf[b][zr][0] + u0);
                const float4 a1 = *(const float4*)((const char*)&zbuf[b][zr][0] + u1);
                sqa[mt] = fmaf(a0.x, a0.x, sqa[mt]); sqb[mt] = fmaf(a0.y, a0.y, sqb[mt]);
                sqa[mt] = fmaf(a0.z, a0.z, sqa[mt]); sqb[mt] = fmaf(a0.w, a0.w, sqb[mt]);
                sqa[mt] = fmaf(a1.x, a1.x, sqa[mt]); sqb[mt] = fmaf(a1.y, a1.y, sqb[mt]);
                sqa[mt] = fmaf(a1.z, a1.z, sqa[mt]); sqb[mt] = fmaf(a1.w, a1.w, sqb[mt]);
                bf16x8 af;
                af[0] = f2bf(a0.x); af[1] = f2bf(a0.y); af[2] = f2bf(a0.z); af[3] = f2bf(a0.w);
                af[4] = f2bf(a1.x); af[5] = f2bf(a1.y); af[6] = f2bf(a1.z); af[7] = f2bf(a1.w);
                acc[mt] = __builtin_amdgcn_mfma_f32_16x16x32_bf16(af, bf, acc[mt], 0, 0, 0);
            }
        }
        __builtin_amdgcn_s_barrier();                // all waves done reading buf
        if (c + 2 < NCH) STAGE(c + 2);
    }

    // norms + similarity write. C layout: lane holds D[lg*4+j][lr].
    const float en = enorm[w * 16 + lr];
#pragma unroll
    for (int mt = 0; mt < 2; ++mt) {
        float ss = sqa[mt] + sqb[mt];
        ss += __shfl_xor(ss, 16);
        ss += __shfl_xor(ss, 32);
        const float zn = sqrtf(ss);                  // ||z[base+mt*16+lr]||
#pragma unroll
        for (int j = 0; j < 4; ++j) {
            const float znj = __shfl(zn, lg * 4 + j);
            out_sim[(size_t)(base + mt * 16 + lg * 4 + j) * NEXP + w * 16 + lr]
                = acc[mt][j] / fmaxf(znj * en, 1e-8f);
        }
    }
}

// ---------------- Kernel 2: softmax + weighted combine — R6 version ---------
__global__ __launch_bounds__(256) void moe_kernel(
    const float* __restrict__ sim,    // [32768][64]
    const short* __restrict__ ekT,    // [2048][64] bf16
    float* __restrict__ out_wei)      // [32768][2048]
{
    const int tid = threadIdx.x;
    const int w   = tid >> 6;
    const int l   = tid & 63;
    const int lr  = l & 15;
    const int lg  = l >> 4;
    const int base = blockIdx.x * 32;
    const int col0 = blockIdx.y * 1024 + w * 256;

    __shared__ __align__(16) short WL[32][64];      // [row][e], 16B-unit XOR swizzled
    __shared__ __align__(16) float tbuf[4][32][68]; // per-wave transpose buffer

    {   // softmax: thread t -> row t>>3, experts (t&7)*8..+8
        const int r  = tid >> 3;
        const int cc = tid & 7;
        const float* sp = sim + (size_t)(base + r) * NEXP + cc * 8;
        const float4 v0 = *(const float4*)sp;
        const float4 v1 = *(const float4*)(sp + 4);
        float va[8] = {v0.x, v0.y, v0.z, v0.w, v1.x, v1.y, v1.z, v1.w};
        float m = va[0];
#pragma unroll
        for (int i = 1; i < 8; ++i) m = fmaxf(m, va[i]);
        m = fmaxf(m, __shfl_xor(m, 1));
        m = fmaxf(m, __shfl_xor(m, 2));
        m = fmaxf(m, __shfl_xor(m, 4));
        float sum = 0.f;
#pragma unroll
        for (int i = 0; i < 8; ++i) { va[i] = __expf(va[i] - m); sum += va[i]; }
        sum += __shfl_xor(sum, 1);
        sum += __shfl_xor(sum, 2);
        sum += __shfl_xor(sum, 4);
        const float inv = 1.0f / sum;
        bf16x8 wv;
#pragma unroll
        for (int i = 0; i < 8; ++i) wv[i] = f2bf(va[i] * inv);
        *(bf16x8*)&WL[r][(cc ^ (r & 7)) * 8] = wv;
    }
    __syncthreads();

    bf16x8 afr[2][2];
#pragma unroll
    for (int mt = 0; mt < 2; ++mt)
#pragma unroll
        for (int ks = 0; ks < 2; ++ks) {
            const int row = mt * 16 + lr;
            const int u   = (ks * 4 + lg) ^ (row & 7);
            afr[mt][ks] = *(const bf16x8*)&WL[row][u * 8];
        }

#pragma unroll 1
    for (int g = 0; g < 4; ++g) {
        f32x4 oacc[4][2];   // [nt2][mt]
#pragma unroll
        for (int nt2 = 0; nt2 < 4; ++nt2) {
            const int d0 = col0 + g * 64 + nt2 * 16;
            const short* bp = ekT + (size_t)(d0 + lr) * NEXP + lg * 8;
            const bf16x8 b0 = *(const bf16x8*)bp;
            const bf16x8 b1 = *(const bf16x8*)(bp + 32);
#pragma unroll
            for (int mt = 0; mt < 2; ++mt) {
                f32x4 o = f32x4{0.f, 0.f, 0.f, 0.f};
                o = __builtin_amdgcn_mfma_f32_16x16x32_bf16(afr[mt][0], b0, o, 0, 0, 0);
                o = __builtin_amdgcn_mfma_f32_16x16x32_bf16(afr[mt][1], b1, o, 0, 0, 0);
                oacc[nt2][mt] = o;
            }
        }
#pragma unroll
        for (int nt2 = 0; nt2 < 4; ++nt2)
#pragma unroll
            for (int mt = 0; mt < 2; ++mt)
#pragma unroll
                for (int j = 0; j < 4; ++j)
                    tbuf[w][mt * 16 + lg * 4 + j][nt2 * 16 + lr] = oacc[nt2][mt][j];
#pragma unroll
        for (int i = 0; i < 8; ++i) {
            const int row  = (l >> 4) + i * 4;
            const int unit = l & 15;
            const float4 t = *(const float4*)&tbuf[w][row][unit * 4];
            *(float4*)&out_wei[(size_t)(base + row) * DIM + col0 + g * 64 + unit * 4] = t;
        }
    }
}

// ---------------- launch -----------------------------------------------------
// ATTRIBUTION PROBE (this round only): sim_kernel is idempotent, so it is
// launched TWICE. dur_us(this round) - 147.5 ~= sim_kernel duration.
extern "C" void kernel_launch(void* const* d_in, const int* in_sizes, int n_in,
                              void* d_out, int out_size, void* d_ws, size_t ws_size,
                              hipStream_t stream) {
    const float* z  = (const float*)d_in[0];
    const float* ek = (const float*)d_in[1];
    float* out_sim = (float*)d_out;
    float* out_wei = out_sim + (size_t)NROWS * NEXP;

    short* ekbf  = (short*)d_ws;                 // 256 KiB
    short* ekT   = ekbf + NEXP * DIM;            // 256 KiB
    float* enorm = (float*)(ekT + DIM * NEXP);   // 256 B

    prep_experts<<<NEXP, 256, 0, stream>>>(ek, ekbf, ekT, enorm);
    sim_kernel<<<NROWS / 32, 256, 0, stream>>>(z, ekbf, enorm, out_sim);
    sim_kernel<<<NROWS / 32, 256, 0, stream>>>(z, ekbf, enorm, out_sim);  // probe duplicate
    moe_kernel<<<dim3(NROWS / 32, 2), 256, 0, stream>>>(out_sim, ekT, out_wei);
}

// Round 12
// 130.703 us; speedup vs baseline: 1.7318x; 1.7318x over previous
//
#include <hip/hip_runtime.h>
#include <hip/hip_bf16.h>

typedef __attribute__((ext_vector_type(4))) float f32x4;
typedef __attribute__((ext_vector_type(8))) short bf16x8;

#define NROWS 32768
#define DIM   2048
#define NEXP  64
#define BKF   128              // K-chunk (f32 elements)
#define NCH   (DIM / BKF)      // 16 chunks

__device__ __forceinline__ short f2bf(float f) {
    __hip_bfloat16 h = __float2bfloat16(f);   // RTNE
    short s;
    __builtin_memcpy(&s, &h, 2);
    return s;
}

// async global->LDS DMA, 16B per lane; LDS dest wave-uniform (HW adds lane*16).
__device__ __forceinline__ void async16(const void* g, void* l) {
    __builtin_amdgcn_global_load_lds(
        (const __attribute__((address_space(1))) unsigned int*)g,
        (__attribute__((address_space(3))) unsigned int*)l, 16, 0, 0);
}

// ---------------- Kernel A: expert prep -------------------------------------
__global__ __launch_bounds__(256) void prep_experts(
    const float* __restrict__ ek,
    short* __restrict__ ekbf,
    short* __restrict__ ekT,
    float* __restrict__ enorm)
{
    const int e = blockIdx.x;
    const int t = threadIdx.x;
    const float* row = ek + e * DIM;
    float ss = 0.f;
#pragma unroll
    for (int i = 0; i < 2; ++i) {
        const int c4 = t + i * 256;
        const float4 v = ((const float4*)row)[c4];
        ss += v.x * v.x + v.y * v.y + v.z * v.z + v.w * v.w;
        short4 b;
        b.x = f2bf(v.x); b.y = f2bf(v.y); b.z = f2bf(v.z); b.w = f2bf(v.w);
        *(short4*)(ekbf + e * DIM + c4 * 4) = b;
        const int d = c4 * 4;
        ekT[(d + 0) * NEXP + e] = b.x;
        ekT[(d + 1) * NEXP + e] = b.y;
        ekT[(d + 2) * NEXP + e] = b.z;
        ekT[(d + 3) * NEXP + e] = b.w;
    }
#pragma unroll
    for (int s = 1; s < 64; s <<= 1) ss += __shfl_xor(ss, s);
    __shared__ float red[4];
    if ((t & 63) == 0) red[t >> 6] = ss;
    __syncthreads();
    if (t == 0) enorm[e] = sqrtf(red[0] + red[1] + red[2] + red[3]);
}

// ---------------- Fused kernel: sim (R6) + softmax + weighted combine -------
// 32 rows/block, 1024 blocks, 4 waves. Phase 1 = R6 sim verbatim (DMA-staged
// z+ek, vmcnt(8), 2 barriers/chunk); sim -> out_sim AND simL (LDS). Phase 2 =
// R6 moe verbatim (softmax -> WL, MFMA vs ekT from L2, per-wave LDS transpose,
// 256B-segment stores), wave covers 512 cols in 8 groups. zbuf is UNIONed
// with tbuf (dead by phase 2) so LDS stays <80 KiB -> 2 blocks/CU. Blocks in
// different phases overlap the chip's read and write streams.
__global__ __launch_bounds__(256) void fused_kernel(
    const float* __restrict__ z,
    const short* __restrict__ ekbf,   // [64][2048] bf16
    const short* __restrict__ ekT,    // [2048][64] bf16
    const float* __restrict__ enorm,  // [64]
    float* __restrict__ out_sim,      // [32768][64]
    float* __restrict__ out_wei)      // [32768][2048]
{
    const int tid = threadIdx.x;
    const int w   = tid >> 6;
    const int l   = tid & 63;
    const int lr  = l & 15;
    const int lg  = l >> 4;
    const int base = blockIdx.x * 32;

    union SmemU {
        float zbuf[2][32][BKF];     // 32 KiB   (phase 1)
        float tbuf[4][32][68];      // 34.8 KiB (phase 2)
    };
    __shared__ __align__(16) SmemU U;                 // 34.8 KiB
    __shared__ __align__(16) short ebuf[2][64][BKF];  // 32 KiB
    __shared__ __align__(16) float simL[32][64];      // 8 KiB
    __shared__ __align__(16) short WL[32][64];        // 4 KiB

    // ================= Phase 1: similarity (R6 verbatim) ====================
    f32x4 acc[2];
    acc[0] = f32x4{0.f, 0.f, 0.f, 0.f};
    acc[1] = f32x4{0.f, 0.f, 0.f, 0.f};
    float sqa[2] = {0.f, 0.f}, sqb[2] = {0.f, 0.f};

    auto STAGE = [&](int c_) {
        const int b_ = c_ & 1;
#pragma unroll
        for (int i = 0; i < 4; ++i) {               // z rows w*8 .. w*8+7
            const int r0 = w * 8 + i * 2;
            const int zr = r0 + (l >> 5);           // 2 rows/instr (512B each)
            async16(z + (size_t)(base + zr) * DIM + c_ * BKF
                      + (((l & 31) ^ (zr & 7)) << 2),
                    &U.zbuf[b_][r0][0]);
        }
#pragma unroll
        for (int i = 0; i < 4; ++i) {               // ek rows w*16 .. w*16+15
            const int r0 = w * 16 + i * 4;
            const int er = r0 + (l >> 4);           // 4 rows/instr (256B each)
            async16(ekbf + (size_t)er * DIM + c_ * BKF
                         + (((l & 15) ^ (er & 7)) << 3),
                    &ebuf[b_][r0][0]);
        }
    };

    STAGE(0); STAGE(1);                              // 16 DMAs/wave in flight

    for (int c = 0; c < NCH; ++c) {
        if (c < NCH - 1) asm volatile("s_waitcnt vmcnt(8)" ::: "memory");
        else             asm volatile("s_waitcnt vmcnt(0)" ::: "memory");
        __builtin_amdgcn_s_barrier();
        __builtin_amdgcn_sched_barrier(0);
        const int b = c & 1;

#pragma unroll
        for (int kk = 0; kk < BKF / 32; ++kk) {
            const int eu = ((kk * 4 + lg) ^ (lr & 7)) << 4;
            const bf16x8 bf =
                *(const bf16x8*)((const char*)&ebuf[b][w * 16 + lr][0] + eu);
#pragma unroll
            for (int mt = 0; mt < 2; ++mt) {
                const int zr = mt * 16 + lr;
                const int u0 = ((kk * 8 + lg * 2)     ^ (lr & 7)) << 4;
                const int u1 = ((kk * 8 + lg * 2 + 1) ^ (lr & 7)) << 4;
                const float4 a0 = *(const float4*)((const char*)&U.zbuf[b][zr][0] + u0);
                const float4 a1 = *(const float4*)((const char*)&U.zbuf[b][zr][0] + u1);
                sqa[mt] = fmaf(a0.x, a0.x, sqa[mt]); sqb[mt] = fmaf(a0.y, a0.y, sqb[mt]);
                sqa[mt] = fmaf(a0.z, a0.z, sqa[mt]); sqb[mt] = fmaf(a0.w, a0.w, sqb[mt]);
                sqa[mt] = fmaf(a1.x, a1.x, sqa[mt]); sqb[mt] = fmaf(a1.y, a1.y, sqb[mt]);
                sqa[mt] = fmaf(a1.z, a1.z, sqa[mt]); sqb[mt] = fmaf(a1.w, a1.w, sqb[mt]);
                bf16x8 af;
                af[0] = f2bf(a0.x); af[1] = f2bf(a0.y); af[2] = f2bf(a0.z); af[3] = f2bf(a0.w);
                af[4] = f2bf(a1.x); af[5] = f2bf(a1.y); af[6] = f2bf(a1.z); af[7] = f2bf(a1.w);
                acc[mt] = __builtin_amdgcn_mfma_f32_16x16x32_bf16(af, bf, acc[mt], 0, 0, 0);
            }
        }
        __builtin_amdgcn_s_barrier();                // all waves done reading buf
        if (c + 2 < NCH) STAGE(c + 2);
    }

    // norms + similarity: write to global AND to simL for phase 2.
    const float en = enorm[w * 16 + lr];
#pragma unroll
    for (int mt = 0; mt < 2; ++mt) {
        float ss = sqa[mt] + sqb[mt];
        ss += __shfl_xor(ss, 16);
        ss += __shfl_xor(ss, 32);
        const float zn = sqrtf(ss);                  // ||z[base+mt*16+lr]||
#pragma unroll
        for (int j = 0; j < 4; ++j) {
            const float znj = __shfl(zn, lg * 4 + j);
            const float sv = acc[mt][j] / fmaxf(znj * en, 1e-8f);
            out_sim[(size_t)(base + mt * 16 + lg * 4 + j) * NEXP + w * 16 + lr] = sv;
            simL[mt * 16 + lg * 4 + j][w * 16 + lr] = sv;
        }
    }
    __syncthreads();   // simL complete; zbuf dead from here (tbuf may alias)

    // ================= Phase 2: softmax + W @ ekT (R6 moe) ==================
    {   // softmax: thread t -> row t>>3, experts (t&7)*8..+8 (from simL)
        const int r  = tid >> 3;
        const int cc = tid & 7;
        const float* sp = &simL[r][cc * 8];
        const f32x4 v0 = *(const f32x4*)sp;
        const f32x4 v1 = *(const f32x4*)(sp + 4);
        float va[8] = {v0[0], v0[1], v0[2], v0[3], v1[0], v1[1], v1[2], v1[3]};
        float m = va[0];
#pragma unroll
        for (int i = 1; i < 8; ++i) m = fmaxf(m, va[i]);
        m = fmaxf(m, __shfl_xor(m, 1));
        m = fmaxf(m, __shfl_xor(m, 2));
        m = fmaxf(m, __shfl_xor(m, 4));
        float sum = 0.f;
#pragma unroll
        for (int i = 0; i < 8; ++i) { va[i] = __expf(va[i] - m); sum += va[i]; }
        sum += __shfl_xor(sum, 1);
        sum += __shfl_xor(sum, 2);
        sum += __shfl_xor(sum, 4);
        const float inv = 1.0f / sum;
        bf16x8 wv;
#pragma unroll
        for (int i = 0; i < 8; ++i) wv[i] = f2bf(va[i] * inv);
        *(bf16x8*)&WL[r][(cc ^ (r & 7)) * 8] = wv;
    }
    __syncthreads();

    bf16x8 afr[2][2];
#pragma unroll
    for (int mt = 0; mt < 2; ++mt)
#pragma unroll
        for (int ks = 0; ks < 2; ++ks) {
            const int row = mt * 16 + lr;
            const int u   = (ks * 4 + lg) ^ (row & 7);
            afr[mt][ks] = *(const bf16x8*)&WL[row][u * 8];
        }

    // wave w owns cols w*512 .. w*512+512 in 8 groups of 64
#pragma unroll 1
    for (int g = 0; g < 8; ++g) {
        f32x4 oacc[4][2];   // [nt2][mt]
#pragma unroll
        for (int nt2 = 0; nt2 < 4; ++nt2) {
            const int d0 = w * 512 + g * 64 + nt2 * 16;
            const short* bp = ekT + (size_t)(d0 + lr) * NEXP + lg * 8;
            const bf16x8 b0 = *(const bf16x8*)bp;
            const bf16x8 b1 = *(const bf16x8*)(bp + 32);
#pragma unroll
            for (int mt = 0; mt < 2; ++mt) {
                f32x4 o = f32x4{0.f, 0.f, 0.f, 0.f};
                o = __builtin_amdgcn_mfma_f32_16x16x32_bf16(afr[mt][0], b0, o, 0, 0, 0);
                o = __builtin_amdgcn_mfma_f32_16x16x32_bf16(afr[mt][1], b1, o, 0, 0, 0);
                oacc[nt2][mt] = o;
            }
        }
#pragma unroll
        for (int nt2 = 0; nt2 < 4; ++nt2)
#pragma unroll
            for (int mt = 0; mt < 2; ++mt)
#pragma unroll
                for (int j = 0; j < 4; ++j)
                    U.tbuf[w][mt * 16 + lg * 4 + j][nt2 * 16 + lr] = oacc[nt2][mt][j];
#pragma unroll
        for (int i = 0; i < 8; ++i) {
            const int row  = (l >> 4) + i * 4;
            const int unit = l & 15;
            const float4 t = *(const float4*)&U.tbuf[w][row][unit * 4];
            *(float4*)&out_wei[(size_t)(base + row) * DIM + w * 512 + g * 64 + unit * 4] = t;
        }
        // no cross-wave hazard: tbuf slice is per-wave; next-g writes follow
        // this wave's own reads in program order.
    }
}

// ---------------- launch -----------------------------------------------------
extern "C" void kernel_launch(void* const* d_in, const int* in_sizes, int n_in,
                              void* d_out, int out_size, void* d_ws, size_t ws_size,
                              hipStream_t stream) {
    const float* z  = (const float*)d_in[0];
    const float* ek = (const float*)d_in[1];
    float* out_sim = (float*)d_out;
    float* out_wei = out_sim + (size_t)NROWS * NEXP;

    short* ekbf  = (short*)d_ws;                 // 256 KiB
    short* ekT   = ekbf + NEXP * DIM;            // 256 KiB
    float* enorm = (float*)(ekT + DIM * NEXP);   // 256 B

    prep_experts<<<NEXP, 256, 0, stream>>>(ek, ekbf, ekT, enorm);
    fused_kernel<<<NROWS / 32, 256, 0, stream>>>(z, ekbf, ekT, enorm, out_sim, out_wei);
}